// Round 1
// baseline (196.259 us; speedup 1.0000x reference)
//
#include <hip/hip_runtime.h>
#include <math.h>

// MultiHeadAttention: B=2, T=2048, C=1024, H=16, D=64, causal, fp32 in/out.
// R12: gemm_qkv rework (the 52us top kernel, MfmaUtil 17%):
//  - depth-2 software pipeline: 3 LDS buffers, raw s_barrier + counted
//    s_waitcnt vmcnt(4) lgkmcnt(0) (loads stay in flight across barriers;
//    never drain vmcnt to 0 in the main loop).
//  - chunk-XOR LDS swizzle (both-sides: pre-swizzled global source, linear
//    LDS dest for global_load_lds, XOR'd ds_read slot) -> 8-way bank
//    conflict on ds_read_b128 drops to 2-way (free).
//  - XCD cell remap: 1-D grid 768, p%8 = XCD, each XCD owns 8m x 12n cell
//    (A 2MB + B 3MB = 5MB working set vs 7MB before).
// attn / gemm_out / cvt unchanged from R11 (attribution discipline).

#define BLOCK 256

typedef __attribute__((ext_vector_type(8))) short bf16x8;
typedef __attribute__((ext_vector_type(4))) float f32x4;
typedef __attribute__((ext_vector_type(16))) float f32x16;

__device__ inline short f2bf(float f) {
  union { float f; unsigned u; } c; c.f = f;
  unsigned u = c.u;
  unsigned r = (u + 0x7fffu + ((u >> 16) & 1u)) >> 16;  // RNE
  return (short)r;
}

// async global->LDS, 16B per lane; LDS dest must be wave-uniform base + lane*16
#define GLD_LDS16(g, l)                                            \
  __builtin_amdgcn_global_load_lds(                                \
      (const __attribute__((address_space(1))) unsigned int*)(g),  \
      (__attribute__((address_space(3))) unsigned int*)(l), 16, 0, 0)

// ---------------- fused conversion kernel ----------------
// z = 0..3: W transpose (Wq/Wk/Wv/Wo -> [n][k] bf16); z = 4..5: x -> bf16.

__global__ void cvt_all_kernel(const float* __restrict__ x,
                               const float* __restrict__ Wq, const float* __restrict__ Wk,
                               const float* __restrict__ Wv, const float* __restrict__ Wo,
                               short* __restrict__ xb,
                               short* __restrict__ Wtqkv, short* __restrict__ Wto) {
  int z = blockIdx.z;
  if (z >= 4) {  // x conversion: 2048 virtual blocks x 256 thr x 8 elems
    int blk = blockIdx.x + (blockIdx.y << 5) + ((z - 4) << 10);
    int i = (blk * 256 + threadIdx.x) * 8;
    float4 a = *(const float4*)(x + i);
    float4 b = *(const float4*)(x + i + 4);
    alignas(16) short o[8];
    o[0] = f2bf(a.x); o[1] = f2bf(a.y); o[2] = f2bf(a.z); o[3] = f2bf(a.w);
    o[4] = f2bf(b.x); o[5] = f2bf(b.y); o[6] = f2bf(b.z); o[7] = f2bf(b.w);
    *(int4*)(xb + i) = *(int4*)o;
    return;
  }
  __shared__ float tile[32][33];
  const float* W = (z == 0) ? Wq : (z == 1) ? Wk : (z == 2) ? Wv : Wo;
  short* outp = (z == 3) ? Wto : (Wtqkv + (size_t)z * 1024 * 1024);
  int k0 = blockIdx.x * 32, n0 = blockIdx.y * 32;
  int tr = threadIdx.x >> 5, tc = threadIdx.x & 31;
#pragma unroll
  for (int i = 0; i < 4; i++)
    tile[tr + i * 8][tc] = W[(k0 + tr + i * 8) * 1024 + n0 + tc];
  __syncthreads();
#pragma unroll
  for (int i = 0; i < 4; i++)
    outp[(n0 + tr + i * 8) * 1024 + k0 + tc] = f2bf(tile[tc][tr + i * 8]);
}

// ---------------- fused QKV GEMM ----------------
// A [4096][1024] bf16 (x), Wt [3072][1024] bf16 (B^T). BK=32.
// Depth-2 pipeline: 3 LDS buffers; step s computes buf s%3 while the loads
// for s+1 and s+2 are in flight (counted vmcnt(4), never 0 mid-loop).
// Q -> [B,H,T,D] prescaled by 0.125*log2(e); K -> [B,H,T,D];
// V -> V^T [B,H,D,T] (natural key order), b64-packed stores.

__global__ __launch_bounds__(BLOCK) void gemm_qkv_kernel(
    const short* __restrict__ A, const short* __restrict__ Wt,
    const float* __restrict__ bq, const float* __restrict__ bk,
    const float* __restrict__ bv,
    short* __restrict__ Qo, short* __restrict__ Ko, short* __restrict__ Vo) {
  const int Kd = 1024;
  const float QSCL = 0.18033688011f;  // 0.125 * log2(e)
  // XCD cell remap: p%8 = XCD (dispatch round-robin heuristic). Each XCD
  // owns an 8m x 12n cell -> A-panel 2MB + B-panel 3MB ~ L2-resident.
  int p = blockIdx.x;
  int xcd = p & 7, j = p >> 3;  // j: 0..95 within the XCD
  int m0 = ((xcd & 3) * 8 + (j & 7)) * 128;
  int n0 = ((xcd >> 2) * 12 + (j >> 3)) * 128;
  int t = threadIdx.x;
  int lane = t & 63, wv = t >> 6;
  int quad = lane >> 4, lc = lane & 15;
  int wy = wv >> 1, wx = wv & 1;
  __shared__ short As[3][128 * 32];
  __shared__ short Bs[3][128 * 32];
  f32x4 acc[4][4] = {};
  int r0 = t >> 2;
  // chunk-XOR swizzle: LDS[row][slot] holds global 16B-chunk slot^((row>>1)&3).
  // (row stride is 64B = 16 banks; XOR with (row>>1)&3 spreads 16-lane groups
  //  across all 8 bank-quads -> 2 lanes/bank = conflict-free.)
  int cs = ((t & 3) ^ ((r0 >> 1) & 3)) * 8;  // pre-swizzled SOURCE chunk
  const short* Arow0 = A + (size_t)(m0 + r0) * Kd + cs;
  const short* Arow1 = A + (size_t)(m0 + r0 + 64) * Kd + cs;  // same xor: (r0+64)>>1 == r0>>1 (mod 4)
  const short* Brow0 = Wt + (size_t)(n0 + r0) * Kd + cs;
  const short* Brow1 = Wt + (size_t)(n0 + r0 + 64) * Kd + cs;
#define STAGE_QKV(buf, koff)                           \
  do {                                                 \
    GLD_LDS16(Arow0 + (koff), &As[buf][8 * t]);        \
    GLD_LDS16(Arow1 + (koff), &As[buf][8 * t + 2048]); \
    GLD_LDS16(Brow0 + (koff), &Bs[buf][8 * t]);        \
    GLD_LDS16(Brow1 + (koff), &Bs[buf][8 * t + 2048]); \
  } while (0)
  // prologue: steps 0 and 1 in flight (8 outstanding vmem ops/wave)
  STAGE_QKV(0, 0);
  asm volatile("" ::: "memory");  // keep the two prologue load groups ordered
  STAGE_QKV(1, 32);
  int xq8 = (quad ^ ((lc >> 1) & 3)) * 8;  // swizzled ds_read slot offset
  int cur = 0, wr = 2;
  for (int step = 0; step < 32; step++) {
    // own step-s loads done (oldest 4 of 8); own prior ds_reads drained
    // (preserves __syncthreads' LDS WAR ordering); steps s+1 loads stay in
    // flight across the barrier.
    if (step < 30)
      asm volatile("s_waitcnt vmcnt(4) lgkmcnt(0)" ::: "memory");
    else
      asm volatile("s_waitcnt vmcnt(0) lgkmcnt(0)" ::: "memory");
    __builtin_amdgcn_s_barrier();
    asm volatile("" ::: "memory");
    if (step + 2 < 32) STAGE_QKV(wr, (step + 2) * 32);
    bf16x8 af[4], bf[4];
#pragma unroll
    for (int i = 0; i < 4; i++)
      af[i] = *(const bf16x8*)&As[cur][(wy * 64 + i * 16 + lc) * 32 + xq8];
#pragma unroll
    for (int i = 0; i < 4; i++)
      bf[i] = *(const bf16x8*)&Bs[cur][(wx * 64 + i * 16 + lc) * 32 + xq8];
#pragma unroll
    for (int mi = 0; mi < 4; mi++)
#pragma unroll
      for (int ni = 0; ni < 4; ni++)
        acc[mi][ni] = __builtin_amdgcn_mfma_f32_16x16x32_bf16(af[mi], bf[ni], acc[mi][ni], 0, 0, 0);
    cur = (cur == 2) ? 0 : cur + 1;
    wr = (wr == 2) ? 0 : wr + 1;
  }
#undef STAGE_QKV
#pragma unroll
  for (int mi = 0; mi < 4; mi++) {
    int row = m0 + wy * 64 + mi * 16 + quad * 4;
#pragma unroll
    for (int ni = 0; ni < 4; ni++) {
      int col = n0 + wx * 64 + ni * 16 + lc;
      int which = col >> 10;  // block-uniform (n-tile never straddles 1024)
      int hd = col & 1023;
      int h = hd >> 6, d = hd & 63;
      float bb = (which == 0) ? bq[hd] : (which == 1) ? bk[hd] : bv[hd];
      if (which == 2) {  // V^T [b,h,d,t], pack 4 consecutive t
        alignas(8) short pk[4];
#pragma unroll
        for (int r = 0; r < 4; r++) pk[r] = f2bf(acc[mi][ni][r] + bb);
        int b = row >> 11, tt = row & 2047;
        *(int2*)&Vo[((size_t)(b * 16 + h) * 64 + d) * 2048 + tt] = *(const int2*)pk;
      } else {
#pragma unroll
        for (int r = 0; r < 4; r++) {
          int rw = row + r;
          int b = rw >> 11, tt = rw & 2047;
          float val = acc[mi][ni][r] + bb;
          if (which == 0) {
            Qo[((size_t)(b * 16 + h) * 2048 + tt) * 64 + d] = f2bf(val * QSCL);
          } else {
            Ko[((size_t)(b * 16 + h) * 2048 + tt) * 64 + d] = f2bf(val);
          }
        }
      }
    }
  }
}

// ---------------- out-projection GEMM ----------------
// A = attended [4096][1024] bf16, Wt = Wo^T [1024][1024], out fp32.
// 64x128 tile, grid (64,8) = 512 blocks; one-barrier LDS dbuf.

__global__ __launch_bounds__(BLOCK) void gemm_out_kernel(
    const short* __restrict__ A, const short* __restrict__ Wt,
    const float* __restrict__ bias, float* __restrict__ Out) {
  const int Kd = 1024;
  int m0 = blockIdx.x * 64, n0 = blockIdx.y * 128;
  int t = threadIdx.x;
  int lane = t & 63, wv = t >> 6;
  int quad = lane >> 4, lc = lane & 15;
  int wy = wv >> 1, wx = wv & 1;  // wave tile: rows wy*32, cols wx*64
  __shared__ short As[2][64 * 32];
  __shared__ short Bs[2][128 * 32];
  int r0 = t >> 2, c0 = (t & 3) * 8;
  f32x4 acc[2][4] = {};
  const short* Arow0 = A + (size_t)(m0 + r0) * Kd + c0;  // r0 covers 0..63
  const short* Brow0 = Wt + (size_t)(n0 + r0) * Kd + c0;
  const short* Brow1 = Wt + (size_t)(n0 + r0 + 64) * Kd + c0;
  GLD_LDS16(Arow0, &As[0][8 * t]);
  GLD_LDS16(Brow0, &Bs[0][8 * t]);
  GLD_LDS16(Brow1, &Bs[0][8 * t + 2048]);
  int cur = 0;
  for (int k0 = 0; k0 < Kd; k0 += 32) {
    __syncthreads();
    if (k0 + 32 < Kd) {
      int nxt = cur ^ 1;
      GLD_LDS16(Arow0 + k0 + 32, &As[nxt][8 * t]);
      GLD_LDS16(Brow0 + k0 + 32, &Bs[nxt][8 * t]);
      GLD_LDS16(Brow1 + k0 + 32, &Bs[nxt][8 * t + 2048]);
    }
    bf16x8 af[2], bf[4];
#pragma unroll
    for (int i = 0; i < 2; i++)
      af[i] = *(const bf16x8*)&As[cur][(wy * 32 + i * 16 + lc) * 32 + quad * 8];
#pragma unroll
    for (int i = 0; i < 4; i++)
      bf[i] = *(const bf16x8*)&Bs[cur][(wx * 64 + i * 16 + lc) * 32 + quad * 8];
#pragma unroll
    for (int mi = 0; mi < 2; mi++)
#pragma unroll
      for (int ni = 0; ni < 4; ni++)
        acc[mi][ni] = __builtin_amdgcn_mfma_f32_16x16x32_bf16(af[mi], bf[ni], acc[mi][ni], 0, 0, 0);
    cur ^= 1;
  }
#pragma unroll
  for (int mi = 0; mi < 2; mi++) {
    int row = m0 + wy * 32 + mi * 16 + quad * 4;
#pragma unroll
    for (int ni = 0; ni < 4; ni++) {
      int col = n0 + wx * 64 + ni * 16 + lc;
      float bb = bias[col];
#pragma unroll
      for (int r = 0; r < 4; r++)
        Out[(size_t)(row + r) * 1024 + col] = acc[mi][ni][r] + bb;
    }
  }
}

// ---------------- flash attention v11 ----------------
// = v10 + XCD-aware block remap: physical block p -> bh = (p&7)*4 + ((p>>3)&3),
// pair = p>>5. All 16 pairs of a bh share p%8 (XCD round-robin heuristic) ->
// that XCD's L2 holds its 4 bh's K+V (4 MB). Grid 512 = 32 bh x 16 pairs;
// strip = 64 q; pair (s, 31-s) -> uniform 33 tiles. 4 waves = qh x kh,
// all active. One-barrier async dbuf; xor-swizzled stride-64 K/V LDS.
// Fixed-max softmax (p = exp2(s2 - 14.5), Q prescaled by 0.125*log2(e)).

__global__ __launch_bounds__(BLOCK, 2) void attn_kernel(
    const short* __restrict__ Q, const short* __restrict__ K,
    const short* __restrict__ Vt, short* __restrict__ Oa) {
  int p = blockIdx.x;
  int bh = ((p & 7) << 2) | ((p >> 3) & 3);  // same bh -> same XCD (p%8)
  int pair = p >> 5;                         // 0..15
  int t = threadIdx.x;
  int lane = t & 63, w = t >> 6;
  int qh = w & 1, kh = w >> 1;
  int ln = lane & 31, lh = lane >> 5;
  const short* Qb = Q + (size_t)bh * 2048 * 64;
  const short* Kb = K + (size_t)bh * 2048 * 64;
  const short* Vg = Vt + (size_t)bh * 64 * 2048;
  int b = bh >> 4, h = bh & 15;

  __shared__ short Kt[2][64 * 64];  // [key][chunk-swizzled d], stride 64
  __shared__ short Vs[2][64 * 64];  // [d][chunk-swizzled key], stride 64
  __shared__ __align__(16) short Ps[4][32 * 72];  // per-wave P; reused as fp32 O-combine
  __shared__ float lx[2][64];
  short* Pw = Ps[w];

  int srow = t >> 3;       // staging row sub-index 0..31 (i*32 + srow = row)
  int sw = t & 7;          // chunk slot 0..7
  const float M2 = 14.5f;  // fixed softmax max, log2 domain
  int xk = ln & 7;         // reader xor (row&7)

  for (int sp = 0; sp < 2; sp++) {
    int s = sp ? (31 - pair) : pair;
    int q0 = s * 64;
    int q0w = q0 + qh * 32;
    int qmaxw = q0w + 31;
    int ntiles = s + 1;

    // Q B-frags (n=q, k=d), 4 chunks of 16 d
    bf16x8 qf[4];
#pragma unroll
    for (int c = 0; c < 4; c++)
      qf[c] = *(const bf16x8*)&Qb[(size_t)(q0w + ln) * 64 + c * 16 + lh * 8];

    f32x16 O0 = {}, O1 = {};
    float lsum = 0.f;

    // prologue: async-stage tile 0 into buf 0 (swizzled: thread t covers
    // row r = i*32 + (t>>3), global chunk cg = (t&7)^(r&7), LDS slot t&7)
#pragma unroll
    for (int i = 0; i < 2; i++) {
      int r = i * 32 + srow;
      int cg = sw ^ (r & 7);
      GLD_LDS16(&Kb[(size_t)r * 64 + cg * 8], &Kt[0][i * 2048 + 8 * t]);
      GLD_LDS16(&Vg[(size_t)r * 2048 + cg * 8], &Vs[0][i * 2048 + 8 * t]);
    }
    int cur = 0;
    for (int kt = 0; kt < ntiles; kt++) {
      __syncthreads();  // drains buf[cur]'s async loads (issued a tile ago)
      if (kt + 1 < ntiles) {
        int kb2 = (kt + 1) * 64;
        int nxt = cur ^ 1;
#pragma unroll
        for (int i = 0; i < 2; i++) {
          int r = i * 32 + srow;
          int cg = sw ^ (r & 7);
          GLD_LDS16(&Kb[(size_t)(kb2 + r) * 64 + cg * 8], &Kt[nxt][i * 2048 + 8 * t]);
          GLD_LDS16(&Vg[(size_t)r * 2048 + kb2 + cg * 8], &Vs[nxt][i * 2048 + 8 * t]);
        }
      }
      int grpbase = kt * 64 + kh * 32;  // wave-uniform 32-key group
      if (grpbase <= qmaxw) {           // wave active on this tile
        // S^T = K(group) * Q^T : C[m=key32][n=q32]
        f32x16 S = {};
#pragma unroll
        for (int c = 0; c < 4; c++) {
          int ch = c * 2 + lh;  // 16B d-chunk index
          bf16x8 kf = *(const bf16x8*)&Kt[cur][(kh * 32 + ln) * 64 + (ch ^ xk) * 8];
          S = __builtin_amdgcn_mfma_f32_32x32x16_bf16(kf, qf[c], S, 0, 0, 0);
        }
        if (kt == ntiles - 1) {  // diagonal tile: mask key > q
          int qg = q0w + ln;
#pragma unroll
          for (int reg = 0; reg < 16; reg++) {
            int key = grpbase + (reg & 3) + 8 * (reg >> 2) + 4 * lh;
            if (key > qg) S[reg] = -3.0e38f;
          }
        }
        // p = exp2(s - M2); accumulate l; pack 4 keys -> b64 (slots 0..31)
#pragma unroll
        for (int g = 0; g < 4; g++) {
          unsigned u[4];
#pragma unroll
          for (int i = 0; i < 4; i++) {
            union { float f; unsigned v; } cc;
            cc.f = __builtin_amdgcn_exp2f(S[g * 4 + i] - M2);
            lsum += cc.f;
            u[i] = cc.v + 0x8000u;  // round-half-up before truncate
          }
          int2 pk;
          pk.x = (int)__builtin_amdgcn_perm(u[1], u[0], 0x07060302);
          pk.y = (int)__builtin_amdgcn_perm(u[3], u[2], 0x07060302);
          *(int2*)&Pw[ln * 72 + g * 8 + lh * 4] = pk;
        }
        // PV over this wave's 32 keys (per-wave LDS, in-order, no barrier)
#pragma unroll
        for (int c2 = 0; c2 < 2; c2++) {
          bf16x8 pf = *(const bf16x8*)&Pw[ln * 72 + c2 * 16 + lh * 8];
          int ch = kh * 4 + c2 * 2 + lh;  // 16B key-chunk within tile
          bf16x8 v0 = *(const bf16x8*)&Vs[cur][ln * 64 + (ch ^ xk) * 8];
          bf16x8 v1 = *(const bf16x8*)&Vs[cur][(32 + ln) * 64 + (ch ^ xk) * 8];
          O0 = __builtin_amdgcn_mfma_f32_32x32x16_bf16(v0, pf, O0, 0, 0, 0);
          O1 = __builtin_amdgcn_mfma_f32_32x32x16_bf16(v1, pf, O1, 0, 0, 0);
        }
      }
      cur ^= 1;
    }

    // ---- combine keyhalf partials through LDS (P region is dead) ----
    float* ob = (float*)&Ps[0][0];  // [qh][((dh*16+reg)*2+lh)*32+ln] fp32
    __syncthreads();                // all P reads done before overwrite
    if (kh == 1) {
      float* obw = ob + qh * 2048;
#pragma unroll
      for (int dh = 0; dh < 2; dh++)
#pragma unroll
        for (int reg = 0; reg < 16; reg++)
          obw[((dh * 16 + reg) * 2 + lh) * 32 + ln] = dh ? O1[reg] : O0[reg];
      lx[qh][lane] = lsum;
    }
    __syncthreads();
    if (kh == 0) {
      float* obw = ob + qh * 2048;
#pragma unroll
      for (int reg = 0; reg < 16; reg++) {
        O0[reg] += obw[((0 * 16 + reg) * 2 + lh) * 32 + ln];
        O1[reg] += obw[((1 * 16 + reg) * 2 + lh) * 32 + ln];
      }
      float lt = lsum + lx[qh][lane];
      lt += __shfl_xor(lt, 32, 64);
      float inv = 1.0f / lt;
      size_t rowbase = (size_t)(b * 2048 + q0w + ln) * 1024 + h * 64;
#pragma unroll
      for (int dh = 0; dh < 2; dh++)
#pragma unroll
        for (int g = 0; g < 4; g++) {
          alignas(8) short pk[4];
#pragma unroll
          for (int i = 0; i < 4; i++) {
            float v = dh ? O1[g * 4 + i] : O0[g * 4 + i];
            pk[i] = f2bf(v * inv);
          }
          *(int2*)&Oa[rowbase + dh * 32 + g * 8 + lh * 4] = *(const int2*)pk;
        }
    }
    // next strip's first __syncthreads orders Ps reuse after ob/lx reads
  }
}

// ---------------- launcher ----------------

extern "C" void kernel_launch(void* const* d_in, const int* in_sizes, int n_in,
                              void* d_out, int out_size, void* d_ws, size_t ws_size,
                              hipStream_t stream) {
  const float* x = (const float*)d_in[0];
  const float* Wq = (const float*)d_in[1];
  const float* bq = (const float*)d_in[2];
  const float* Wk = (const float*)d_in[3];
  const float* bk = (const float*)d_in[4];
  const float* Wv = (const float*)d_in[5];
  const float* bv = (const float*)d_in[6];
  const float* Wo = (const float*)d_in[7];
  const float* bo = (const float*)d_in[8];
  char* ws = (char*)d_ws;
  const size_t MB = 1024 * 1024;
  short* xb = (short*)(ws);               // 8 MiB  [4096][1024] bf16
  short* Wtqkv = (short*)(ws + 8 * MB);   // 6 MiB  [3072][1024] bf16
  short* Wto = (short*)(ws + 14 * MB);    // 2 MiB  [1024][1024] bf16
  short* Qb = (short*)(ws + 17 * MB);     // 8 MiB  [2][16][2048][64] bf16 (prescaled)
  short* Kb = (short*)(ws + 25 * MB);     // 8 MiB  [2][16][2048][64] bf16
  short* Vb = (short*)(ws + 33 * MB);     // 8 MiB  V^T [2][16][64][2048] bf16
  short* Att = (short*)(ws + 41 * MB);    // 8 MiB  [4096][1024] bf16
  float* out = (float*)d_out;

  cvt_all_kernel<<<dim3(32, 32, 6), BLOCK, 0, stream>>>(x, Wq, Wk, Wv, Wo, xb, Wtqkv, Wto);
  gemm_qkv_kernel<<<dim3(768), BLOCK, 0, stream>>>(xb, Wtqkv, bq, bk, bv, Qb, Kb, Vb);
  attn_kernel<<<512, BLOCK, 0, stream>>>(Qb, Kb, Vb, Att);
  gemm_out_kernel<<<dim3(64, 8), BLOCK, 0, stream>>>(Att, Wto, bo, out);
}

// Round 2
// 178.291 us; speedup vs baseline: 1.1008x; 1.1008x over previous
//
#include <hip/hip_runtime.h>
#include <math.h>

// MultiHeadAttention: B=2, T=2048, C=1024, H=16, D=64, causal, fp32 in/out.
// R13: gemm_qkv reg-staged pipeline (T14). R12's counted-vmcnt dbuf was
// NEUTRAL (52us invariant, conflicts 3.1M->0 with no dur change) -> theory:
// compiler inserts vmcnt(0) before ds_reads (can't prove global_load_lds
// writes to As[wr] don't alias As[cur]) -> every K-step exposes full load
// latency regardless of buffering. Fix: no global_load_lds here at all.
//  - global_load -> VGPR (next tile) issued BEFORE compute; ds_write AFTER
//    (compiler puts the vmcnt wait right before ds_write = after compute).
//  - BK=64: 16 steps instead of 32 (half the latency-exposure points).
//  - single 32KB LDS buffer; raw s_barrier + lgkmcnt(0) only (no vmcnt
//    drain at barriers). Chunk-XOR swizzle applied at ds_write.
// attn / gemm_out / cvt unchanged (attribution discipline).

#define BLOCK 256

typedef __attribute__((ext_vector_type(8))) short bf16x8;
typedef __attribute__((ext_vector_type(4))) float f32x4;
typedef __attribute__((ext_vector_type(16))) float f32x16;

__device__ inline short f2bf(float f) {
  union { float f; unsigned u; } c; c.f = f;
  unsigned u = c.u;
  unsigned r = (u + 0x7fffu + ((u >> 16) & 1u)) >> 16;  // RNE
  return (short)r;
}

// async global->LDS, 16B per lane; LDS dest must be wave-uniform base + lane*16
#define GLD_LDS16(g, l)                                            \
  __builtin_amdgcn_global_load_lds(                                \
      (const __attribute__((address_space(1))) unsigned int*)(g),  \
      (__attribute__((address_space(3))) unsigned int*)(l), 16, 0, 0)

// ---------------- fused conversion kernel ----------------
// z = 0..3: W transpose (Wq/Wk/Wv/Wo -> [n][k] bf16); z = 4..5: x -> bf16.

__global__ void cvt_all_kernel(const float* __restrict__ x,
                               const float* __restrict__ Wq, const float* __restrict__ Wk,
                               const float* __restrict__ Wv, const float* __restrict__ Wo,
                               short* __restrict__ xb,
                               short* __restrict__ Wtqkv, short* __restrict__ Wto) {
  int z = blockIdx.z;
  if (z >= 4) {  // x conversion: 2048 virtual blocks x 256 thr x 8 elems
    int blk = blockIdx.x + (blockIdx.y << 5) + ((z - 4) << 10);
    int i = (blk * 256 + threadIdx.x) * 8;
    float4 a = *(const float4*)(x + i);
    float4 b = *(const float4*)(x + i + 4);
    alignas(16) short o[8];
    o[0] = f2bf(a.x); o[1] = f2bf(a.y); o[2] = f2bf(a.z); o[3] = f2bf(a.w);
    o[4] = f2bf(b.x); o[5] = f2bf(b.y); o[6] = f2bf(b.z); o[7] = f2bf(b.w);
    *(int4*)(xb + i) = *(int4*)o;
    return;
  }
  __shared__ float tile[32][33];
  const float* W = (z == 0) ? Wq : (z == 1) ? Wk : (z == 2) ? Wv : Wo;
  short* outp = (z == 3) ? Wto : (Wtqkv + (size_t)z * 1024 * 1024);
  int k0 = blockIdx.x * 32, n0 = blockIdx.y * 32;
  int tr = threadIdx.x >> 5, tc = threadIdx.x & 31;
#pragma unroll
  for (int i = 0; i < 4; i++)
    tile[tr + i * 8][tc] = W[(k0 + tr + i * 8) * 1024 + n0 + tc];
  __syncthreads();
#pragma unroll
  for (int i = 0; i < 4; i++)
    outp[(n0 + tr + i * 8) * 1024 + k0 + tc] = f2bf(tile[tc][tr + i * 8]);
}

// ---------------- fused QKV GEMM (reg-staged, BK=64) ----------------
// A [4096][1024] bf16 (x), Wt [3072][1024] bf16 (B^T).
// Per step: {ds_write staged regs (vmcnt wait lands here) -> barrier ->
// issue next-tile global loads to regs -> compute from LDS -> barrier}.
// Q -> [B,H,T,D] prescaled by 0.125*log2(e); K -> [B,H,T,D];
// V -> V^T [B,H,D,T] (natural key order), b64-packed stores.

__global__ __launch_bounds__(BLOCK, 3) void gemm_qkv_kernel(
    const short* __restrict__ A, const short* __restrict__ Wt,
    const float* __restrict__ bq, const float* __restrict__ bk,
    const float* __restrict__ bv,
    short* __restrict__ Qo, short* __restrict__ Ko, short* __restrict__ Vo) {
  const int Kd = 1024;
  const float QSCL = 0.18033688011f;  // 0.125 * log2(e)
  // XCD cell remap: p%8 = XCD. Each XCD owns an 8m x 12n cell.
  int p = blockIdx.x;
  int xcd = p & 7, j = p >> 3;  // j: 0..95 within the XCD
  int m0 = ((xcd & 3) * 8 + (j & 7)) * 128;
  int n0 = ((xcd >> 2) * 12 + (j >> 3)) * 128;
  int t = threadIdx.x;
  int lane = t & 63, wv = t >> 6;
  int quad = lane >> 4, lc = lane & 15;
  int wy = wv >> 1, wx = wv & 1;
  __shared__ short As[128 * 64];  // [row][slot^swz], 16KB
  __shared__ short Bs[128 * 64];
  f32x4 acc[4][4] = {};

  // staging map: wave wv covers rows wv*32 + i*8 + (lane>>3), chunk lane&7
  int sr = wv * 32 + (lane >> 3);  // base row (i adds i*8; (i*8)&7==0)
  int schk = lane & 7;             // linear global 16B chunk
  const short* Ab = A + (size_t)(m0 + sr) * Kd + schk * 8;
  const short* Bb = Wt + (size_t)(n0 + sr) * Kd + schk * 8;
  // swizzled LDS write slot: slot = chunk ^ (row&7); row&7 == lane>>3
  int wslot = schk ^ (lane >> 3);
  short* wa = &As[sr * 64 + wslot * 8];
  short* wb = &Bs[sr * 64 + wslot * 8];

  bf16x8 sA[4], sB[4];
  // prologue: stage k=0 into regs
#pragma unroll
  for (int i = 0; i < 4; i++) {
    sA[i] = *(const bf16x8*)(Ab + (size_t)(i * 8) * Kd);
    sB[i] = *(const bf16x8*)(Bb + (size_t)(i * 8) * Kd);
  }
  // reader xor: row = wy*64 + i*16 + lc -> row&7 == lc&7
  int rx = lc & 7;
  for (int step = 0; step < 16; step++) {
    // ds_write staged tile (compiler-inserted vmcnt wait sits HERE, after
    // the previous step's full compute phase)
#pragma unroll
    for (int i = 0; i < 4; i++) {
      *(bf16x8*)(wa + i * 8 * 64) = sA[i];
      *(bf16x8*)(wb + i * 8 * 64) = sB[i];
    }
    asm volatile("s_waitcnt lgkmcnt(0)" ::: "memory");  // writes landed
    __builtin_amdgcn_s_barrier();                       // tile visible
    asm volatile("" ::: "memory");
    if (step + 1 < 16) {  // issue next-tile loads; wait is next ds_write
      int koff = (step + 1) * 64;
#pragma unroll
      for (int i = 0; i < 4; i++) {
        sA[i] = *(const bf16x8*)(Ab + (size_t)(i * 8) * Kd + koff);
        sB[i] = *(const bf16x8*)(Bb + (size_t)(i * 8) * Kd + koff);
      }
    }
#pragma unroll
    for (int kc = 0; kc < 2; kc++) {
      bf16x8 af[4], bf[4];
#pragma unroll
      for (int i = 0; i < 4; i++)
        af[i] = *(const bf16x8*)&As[(wy * 64 + i * 16 + lc) * 64 +
                                    ((kc * 4 + quad) ^ rx) * 8];
#pragma unroll
      for (int i = 0; i < 4; i++)
        bf[i] = *(const bf16x8*)&Bs[(wx * 64 + i * 16 + lc) * 64 +
                                    ((kc * 4 + quad) ^ rx) * 8];
#pragma unroll
      for (int mi = 0; mi < 4; mi++)
#pragma unroll
        for (int ni = 0; ni < 4; ni++)
          acc[mi][ni] = __builtin_amdgcn_mfma_f32_16x16x32_bf16(af[mi], bf[ni], acc[mi][ni], 0, 0, 0);
    }
    asm volatile("s_waitcnt lgkmcnt(0)" ::: "memory");  // reads drained
    __builtin_amdgcn_s_barrier();                       // before overwrite
    asm volatile("" ::: "memory");
  }
#pragma unroll
  for (int mi = 0; mi < 4; mi++) {
    int row = m0 + wy * 64 + mi * 16 + quad * 4;
#pragma unroll
    for (int ni = 0; ni < 4; ni++) {
      int col = n0 + wx * 64 + ni * 16 + lc;
      int which = col >> 10;  // block-uniform (n-tile never straddles 1024)
      int hd = col & 1023;
      int h = hd >> 6, d = hd & 63;
      float bb = (which == 0) ? bq[hd] : (which == 1) ? bk[hd] : bv[hd];
      if (which == 2) {  // V^T [b,h,d,t], pack 4 consecutive t
        alignas(8) short pk[4];
#pragma unroll
        for (int r = 0; r < 4; r++) pk[r] = f2bf(acc[mi][ni][r] + bb);
        int b = row >> 11, tt = row & 2047;
        *(int2*)&Vo[((size_t)(b * 16 + h) * 64 + d) * 2048 + tt] = *(const int2*)pk;
      } else {
#pragma unroll
        for (int r = 0; r < 4; r++) {
          int rw = row + r;
          int b = rw >> 11, tt = rw & 2047;
          float val = acc[mi][ni][r] + bb;
          if (which == 0) {
            Qo[((size_t)(b * 16 + h) * 2048 + tt) * 64 + d] = f2bf(val * QSCL);
          } else {
            Ko[((size_t)(b * 16 + h) * 2048 + tt) * 64 + d] = f2bf(val);
          }
        }
      }
    }
  }
}

// ---------------- out-projection GEMM ----------------
// A = attended [4096][1024] bf16, Wt = Wo^T [1024][1024], out fp32.
// 64x128 tile, grid (64,8) = 512 blocks; one-barrier LDS dbuf.

__global__ __launch_bounds__(BLOCK) void gemm_out_kernel(
    const short* __restrict__ A, const short* __restrict__ Wt,
    const float* __restrict__ bias, float* __restrict__ Out) {
  const int Kd = 1024;
  int m0 = blockIdx.x * 64, n0 = blockIdx.y * 128;
  int t = threadIdx.x;
  int lane = t & 63, wv = t >> 6;
  int quad = lane >> 4, lc = lane & 15;
  int wy = wv >> 1, wx = wv & 1;  // wave tile: rows wy*32, cols wx*64
  __shared__ short As[2][64 * 32];
  __shared__ short Bs[2][128 * 32];
  int r0 = t >> 2, c0 = (t & 3) * 8;
  f32x4 acc[2][4] = {};
  const short* Arow0 = A + (size_t)(m0 + r0) * Kd + c0;  // r0 covers 0..63
  const short* Brow0 = Wt + (size_t)(n0 + r0) * Kd + c0;
  const short* Brow1 = Wt + (size_t)(n0 + r0 + 64) * Kd + c0;
  GLD_LDS16(Arow0, &As[0][8 * t]);
  GLD_LDS16(Brow0, &Bs[0][8 * t]);
  GLD_LDS16(Brow1, &Bs[0][8 * t + 2048]);
  int cur = 0;
  for (int k0 = 0; k0 < Kd; k0 += 32) {
    __syncthreads();
    if (k0 + 32 < Kd) {
      int nxt = cur ^ 1;
      GLD_LDS16(Arow0 + k0 + 32, &As[nxt][8 * t]);
      GLD_LDS16(Brow0 + k0 + 32, &Bs[nxt][8 * t]);
      GLD_LDS16(Brow1 + k0 + 32, &Bs[nxt][8 * t + 2048]);
    }
    bf16x8 af[2], bf[4];
#pragma unroll
    for (int i = 0; i < 2; i++)
      af[i] = *(const bf16x8*)&As[cur][(wy * 32 + i * 16 + lc) * 32 + quad * 8];
#pragma unroll
    for (int i = 0; i < 4; i++)
      bf[i] = *(const bf16x8*)&Bs[cur][(wx * 64 + i * 16 + lc) * 32 + quad * 8];
#pragma unroll
    for (int mi = 0; mi < 2; mi++)
#pragma unroll
      for (int ni = 0; ni < 4; ni++)
        acc[mi][ni] = __builtin_amdgcn_mfma_f32_16x16x32_bf16(af[mi], bf[ni], acc[mi][ni], 0, 0, 0);
    cur ^= 1;
  }
#pragma unroll
  for (int mi = 0; mi < 2; mi++) {
    int row = m0 + wy * 32 + mi * 16 + quad * 4;
#pragma unroll
    for (int ni = 0; ni < 4; ni++) {
      int col = n0 + wx * 64 + ni * 16 + lc;
      float bb = bias[col];
#pragma unroll
      for (int r = 0; r < 4; r++)
        Out[(size_t)(row + r) * 1024 + col] = acc[mi][ni][r] + bb;
    }
  }
}

// ---------------- flash attention v11 ----------------
// = v10 + XCD-aware block remap: physical block p -> bh = (p&7)*4 + ((p>>3)&3),
// pair = p>>5. All 16 pairs of a bh share p%8 (XCD round-robin heuristic) ->
// that XCD's L2 holds its 4 bh's K+V (4 MB). Grid 512 = 32 bh x 16 pairs;
// strip = 64 q; pair (s, 31-s) -> uniform 33 tiles. 4 waves = qh x kh,
// all active. One-barrier async dbuf; xor-swizzled stride-64 K/V LDS.
// Fixed-max softmax (p = exp2(s2 - 14.5), Q prescaled by 0.125*log2(e)).

__global__ __launch_bounds__(BLOCK, 2) void attn_kernel(
    const short* __restrict__ Q, const short* __restrict__ K,
    const short* __restrict__ Vt, short* __restrict__ Oa) {
  int p = blockIdx.x;
  int bh = ((p & 7) << 2) | ((p >> 3) & 3);  // same bh -> same XCD (p%8)
  int pair = p >> 5;                         // 0..15
  int t = threadIdx.x;
  int lane = t & 63, w = t >> 6;
  int qh = w & 1, kh = w >> 1;
  int ln = lane & 31, lh = lane >> 5;
  const short* Qb = Q + (size_t)bh * 2048 * 64;
  const short* Kb = K + (size_t)bh * 2048 * 64;
  const short* Vg = Vt + (size_t)bh * 64 * 2048;
  int b = bh >> 4, h = bh & 15;

  __shared__ short Kt[2][64 * 64];  // [key][chunk-swizzled d], stride 64
  __shared__ short Vs[2][64 * 64];  // [d][chunk-swizzled key], stride 64
  __shared__ __align__(16) short Ps[4][32 * 72];  // per-wave P; reused as fp32 O-combine
  __shared__ float lx[2][64];
  short* Pw = Ps[w];

  int srow = t >> 3;       // staging row sub-index 0..31 (i*32 + srow = row)
  int sw = t & 7;          // chunk slot 0..7
  const float M2 = 14.5f;  // fixed softmax max, log2 domain
  int xk = ln & 7;         // reader xor (row&7)

  for (int sp = 0; sp < 2; sp++) {
    int s = sp ? (31 - pair) : pair;
    int q0 = s * 64;
    int q0w = q0 + qh * 32;
    int qmaxw = q0w + 31;
    int ntiles = s + 1;

    // Q B-frags (n=q, k=d), 4 chunks of 16 d
    bf16x8 qf[4];
#pragma unroll
    for (int c = 0; c < 4; c++)
      qf[c] = *(const bf16x8*)&Qb[(size_t)(q0w + ln) * 64 + c * 16 + lh * 8];

    f32x16 O0 = {}, O1 = {};
    float lsum = 0.f;

    // prologue: async-stage tile 0 into buf 0 (swizzled: thread t covers
    // row r = i*32 + (t>>3), global chunk cg = (t&7)^(r&7), LDS slot t&7)
#pragma unroll
    for (int i = 0; i < 2; i++) {
      int r = i * 32 + srow;
      int cg = sw ^ (r & 7);
      GLD_LDS16(&Kb[(size_t)r * 64 + cg * 8], &Kt[0][i * 2048 + 8 * t]);
      GLD_LDS16(&Vg[(size_t)r * 2048 + cg * 8], &Vs[0][i * 2048 + 8 * t]);
    }
    int cur = 0;
    for (int kt = 0; kt < ntiles; kt++) {
      __syncthreads();  // drains buf[cur]'s async loads (issued a tile ago)
      if (kt + 1 < ntiles) {
        int kb2 = (kt + 1) * 64;
        int nxt = cur ^ 1;
#pragma unroll
        for (int i = 0; i < 2; i++) {
          int r = i * 32 + srow;
          int cg = sw ^ (r & 7);
          GLD_LDS16(&Kb[(size_t)(kb2 + r) * 64 + cg * 8], &Kt[nxt][i * 2048 + 8 * t]);
          GLD_LDS16(&Vg[(size_t)r * 2048 + kb2 + cg * 8], &Vs[nxt][i * 2048 + 8 * t]);
        }
      }
      int grpbase = kt * 64 + kh * 32;  // wave-uniform 32-key group
      if (grpbase <= qmaxw) {           // wave active on this tile
        // S^T = K(group) * Q^T : C[m=key32][n=q32]
        f32x16 S = {};
#pragma unroll
        for (int c = 0; c < 4; c++) {
          int ch = c * 2 + lh;  // 16B d-chunk index
          bf16x8 kf = *(const bf16x8*)&Kt[cur][(kh * 32 + ln) * 64 + (ch ^ xk) * 8];
          S = __builtin_amdgcn_mfma_f32_32x32x16_bf16(kf, qf[c], S, 0, 0, 0);
        }
        if (kt == ntiles - 1) {  // diagonal tile: mask key > q
          int qg = q0w + ln;
#pragma unroll
          for (int reg = 0; reg < 16; reg++) {
            int key = grpbase + (reg & 3) + 8 * (reg >> 2) + 4 * lh;
            if (key > qg) S[reg] = -3.0e38f;
          }
        }
        // p = exp2(s - M2); accumulate l; pack 4 keys -> b64 (slots 0..31)
#pragma unroll
        for (int g = 0; g < 4; g++) {
          unsigned u[4];
#pragma unroll
          for (int i = 0; i < 4; i++) {
            union { float f; unsigned v; } cc;
            cc.f = __builtin_amdgcn_exp2f(S[g * 4 + i] - M2);
            lsum += cc.f;
            u[i] = cc.v + 0x8000u;  // round-half-up before truncate
          }
          int2 pk;
          pk.x = (int)__builtin_amdgcn_perm(u[1], u[0], 0x07060302);
          pk.y = (int)__builtin_amdgcn_perm(u[3], u[2], 0x07060302);
          *(int2*)&Pw[ln * 72 + g * 8 + lh * 4] = pk;
        }
        // PV over this wave's 32 keys (per-wave LDS, in-order, no barrier)
#pragma unroll
        for (int c2 = 0; c2 < 2; c2++) {
          bf16x8 pf = *(const bf16x8*)&Pw[ln * 72 + c2 * 16 + lh * 8];
          int ch = kh * 4 + c2 * 2 + lh;  // 16B key-chunk within tile
          bf16x8 v0 = *(const bf16x8*)&Vs[cur][ln * 64 + (ch ^ xk) * 8];
          bf16x8 v1 = *(const bf16x8*)&Vs[cur][(32 + ln) * 64 + (ch ^ xk) * 8];
          O0 = __builtin_amdgcn_mfma_f32_32x32x16_bf16(v0, pf, O0, 0, 0, 0);
          O1 = __builtin_amdgcn_mfma_f32_32x32x16_bf16(v1, pf, O1, 0, 0, 0);
        }
      }
      cur ^= 1;
    }

    // ---- combine keyhalf partials through LDS (P region is dead) ----
    float* ob = (float*)&Ps[0][0];  // [qh][((dh*16+reg)*2+lh)*32+ln] fp32
    __syncthreads();                // all P reads done before overwrite
    if (kh == 1) {
      float* obw = ob + qh * 2048;
#pragma unroll
      for (int dh = 0; dh < 2; dh++)
#pragma unroll
        for (int reg = 0; reg < 16; reg++)
          obw[((dh * 16 + reg) * 2 + lh) * 32 + ln] = dh ? O1[reg] : O0[reg];
      lx[qh][lane] = lsum;
    }
    __syncthreads();
    if (kh == 0) {
      float* obw = ob + qh * 2048;
#pragma unroll
      for (int reg = 0; reg < 16; reg++) {
        O0[reg] += obw[((0 * 16 + reg) * 2 + lh) * 32 + ln];
        O1[reg] += obw[((1 * 16 + reg) * 2 + lh) * 32 + ln];
      }
      float lt = lsum + lx[qh][lane];
      lt += __shfl_xor(lt, 32, 64);
      float inv = 1.0f / lt;
      size_t rowbase = (size_t)(b * 2048 + q0w + ln) * 1024 + h * 64;
#pragma unroll
      for (int dh = 0; dh < 2; dh++)
#pragma unroll
        for (int g = 0; g < 4; g++) {
          alignas(8) short pk[4];
#pragma unroll
          for (int i = 0; i < 4; i++) {
            float v = dh ? O1[g * 4 + i] : O0[g * 4 + i];
            pk[i] = f2bf(v * inv);
          }
          *(int2*)&Oa[rowbase + dh * 32 + g * 8 + lh * 4] = *(const int2*)pk;
        }
    }
    // next strip's first __syncthreads orders Ps reuse after ob/lx reads
  }
}

// ---------------- launcher ----------------

extern "C" void kernel_launch(void* const* d_in, const int* in_sizes, int n_in,
                              void* d_out, int out_size, void* d_ws, size_t ws_size,
                              hipStream_t stream) {
  const float* x = (const float*)d_in[0];
  const float* Wq = (const float*)d_in[1];
  const float* bq = (const float*)d_in[2];
  const float* Wk = (const float*)d_in[3];
  const float* bk = (const float*)d_in[4];
  const float* Wv = (const float*)d_in[5];
  const float* bv = (const float*)d_in[6];
  const float* Wo = (const float*)d_in[7];
  const float* bo = (const float*)d_in[8];
  char* ws = (char*)d_ws;
  const size_t MB = 1024 * 1024;
  short* xb = (short*)(ws);               // 8 MiB  [4096][1024] bf16
  short* Wtqkv = (short*)(ws + 8 * MB);   // 6 MiB  [3072][1024] bf16
  short* Wto = (short*)(ws + 14 * MB);    // 2 MiB  [1024][1024] bf16
  short* Qb = (short*)(ws + 17 * MB);     // 8 MiB  [2][16][2048][64] bf16 (prescaled)
  short* Kb = (short*)(ws + 25 * MB);     // 8 MiB  [2][16][2048][64] bf16
  short* Vb = (short*)(ws + 33 * MB);     // 8 MiB  V^T [2][16][64][2048] bf16
  short* Att = (short*)(ws + 41 * MB);    // 8 MiB  [4096][1024] bf16
  float* out = (float*)d_out;

  cvt_all_kernel<<<dim3(32, 32, 6), BLOCK, 0, stream>>>(x, Wq, Wk, Wv, Wo, xb, Wtqkv, Wto);
  gemm_qkv_kernel<<<dim3(768), BLOCK, 0, stream>>>(xb, Wtqkv, bq, bk, bv, Qb, Kb, Vb);
  attn_kernel<<<512, BLOCK, 0, stream>>>(Qb, Kb, Vb, Att);
  gemm_out_kernel<<<dim3(64, 8), BLOCK, 0, stream>>>(Att, Wto, bo, out);
}

// Round 3
// 171.453 us; speedup vs baseline: 1.1447x; 1.0399x over previous
//
#include <hip/hip_runtime.h>
#include <math.h>

// MultiHeadAttention: B=2, T=2048, C=1024, H=16, D=64, causal, fp32 in/out.
// R14: propagate the R13 reg-staged pipeline (proven: gemm_qkv 52.5 -> <43us)
// to the two remaining global_load_lds kernels:
//  - attn: single-buffer K/V LDS; stage next tile in VGPRs, ds_write after
//    barrier (vmcnt wait lands post-compute); no per-tile vmcnt(0) drain.
//  - gemm_out: same rework + BK=64 (16 steps, was 32 drain points).
// All math stays in ascending-k order -> bitwise-identical results.
// gemm_qkv / cvt unchanged from R13.

#define BLOCK 256

typedef __attribute__((ext_vector_type(8))) short bf16x8;
typedef __attribute__((ext_vector_type(4))) float f32x4;
typedef __attribute__((ext_vector_type(16))) float f32x16;

__device__ inline short f2bf(float f) {
  union { float f; unsigned u; } c; c.f = f;
  unsigned u = c.u;
  unsigned r = (u + 0x7fffu + ((u >> 16) & 1u)) >> 16;  // RNE
  return (short)r;
}

// ---------------- fused conversion kernel ----------------
// z = 0..3: W transpose (Wq/Wk/Wv/Wo -> [n][k] bf16); z = 4..5: x -> bf16.

__global__ void cvt_all_kernel(const float* __restrict__ x,
                               const float* __restrict__ Wq, const float* __restrict__ Wk,
                               const float* __restrict__ Wv, const float* __restrict__ Wo,
                               short* __restrict__ xb,
                               short* __restrict__ Wtqkv, short* __restrict__ Wto) {
  int z = blockIdx.z;
  if (z >= 4) {  // x conversion: 2048 virtual blocks x 256 thr x 8 elems
    int blk = blockIdx.x + (blockIdx.y << 5) + ((z - 4) << 10);
    int i = (blk * 256 + threadIdx.x) * 8;
    float4 a = *(const float4*)(x + i);
    float4 b = *(const float4*)(x + i + 4);
    alignas(16) short o[8];
    o[0] = f2bf(a.x); o[1] = f2bf(a.y); o[2] = f2bf(a.z); o[3] = f2bf(a.w);
    o[4] = f2bf(b.x); o[5] = f2bf(b.y); o[6] = f2bf(b.z); o[7] = f2bf(b.w);
    *(int4*)(xb + i) = *(int4*)o;
    return;
  }
  __shared__ float tile[32][33];
  const float* W = (z == 0) ? Wq : (z == 1) ? Wk : (z == 2) ? Wv : Wo;
  short* outp = (z == 3) ? Wto : (Wtqkv + (size_t)z * 1024 * 1024);
  int k0 = blockIdx.x * 32, n0 = blockIdx.y * 32;
  int tr = threadIdx.x >> 5, tc = threadIdx.x & 31;
#pragma unroll
  for (int i = 0; i < 4; i++)
    tile[tr + i * 8][tc] = W[(k0 + tr + i * 8) * 1024 + n0 + tc];
  __syncthreads();
#pragma unroll
  for (int i = 0; i < 4; i++)
    outp[(n0 + tr + i * 8) * 1024 + k0 + tc] = f2bf(tile[tc][tr + i * 8]);
}

// ---------------- fused QKV GEMM (reg-staged, BK=64) ----------------
// A [4096][1024] bf16 (x), Wt [3072][1024] bf16 (B^T).
// Per step: {ds_write staged regs (vmcnt wait lands here) -> barrier ->
// issue next-tile global loads to regs -> compute from LDS -> barrier}.
// Q -> [B,H,T,D] prescaled by 0.125*log2(e); K -> [B,H,T,D];
// V -> V^T [B,H,D,T] (natural key order), b64-packed stores.

__global__ __launch_bounds__(BLOCK, 3) void gemm_qkv_kernel(
    const short* __restrict__ A, const short* __restrict__ Wt,
    const float* __restrict__ bq, const float* __restrict__ bk,
    const float* __restrict__ bv,
    short* __restrict__ Qo, short* __restrict__ Ko, short* __restrict__ Vo) {
  const int Kd = 1024;
  const float QSCL = 0.18033688011f;  // 0.125 * log2(e)
  // XCD cell remap: p%8 = XCD. Each XCD owns an 8m x 12n cell.
  int p = blockIdx.x;
  int xcd = p & 7, j = p >> 3;  // j: 0..95 within the XCD
  int m0 = ((xcd & 3) * 8 + (j & 7)) * 128;
  int n0 = ((xcd >> 2) * 12 + (j >> 3)) * 128;
  int t = threadIdx.x;
  int lane = t & 63, wv = t >> 6;
  int quad = lane >> 4, lc = lane & 15;
  int wy = wv >> 1, wx = wv & 1;
  __shared__ short As[128 * 64];  // [row][slot^swz], 16KB
  __shared__ short Bs[128 * 64];
  f32x4 acc[4][4] = {};

  // staging map: wave wv covers rows wv*32 + i*8 + (lane>>3), chunk lane&7
  int sr = wv * 32 + (lane >> 3);  // base row (i adds i*8; (i*8)&7==0)
  int schk = lane & 7;             // linear global 16B chunk
  const short* Ab = A + (size_t)(m0 + sr) * Kd + schk * 8;
  const short* Bb = Wt + (size_t)(n0 + sr) * Kd + schk * 8;
  // swizzled LDS write slot: slot = chunk ^ (row&7); row&7 == lane>>3
  int wslot = schk ^ (lane >> 3);
  short* wa = &As[sr * 64 + wslot * 8];
  short* wb = &Bs[sr * 64 + wslot * 8];

  bf16x8 sA[4], sB[4];
  // prologue: stage k=0 into regs
#pragma unroll
  for (int i = 0; i < 4; i++) {
    sA[i] = *(const bf16x8*)(Ab + (size_t)(i * 8) * Kd);
    sB[i] = *(const bf16x8*)(Bb + (size_t)(i * 8) * Kd);
  }
  // reader xor: row = wy*64 + i*16 + lc -> row&7 == lc&7
  int rx = lc & 7;
  for (int step = 0; step < 16; step++) {
    // ds_write staged tile (compiler-inserted vmcnt wait sits HERE, after
    // the previous step's full compute phase)
#pragma unroll
    for (int i = 0; i < 4; i++) {
      *(bf16x8*)(wa + i * 8 * 64) = sA[i];
      *(bf16x8*)(wb + i * 8 * 64) = sB[i];
    }
    asm volatile("s_waitcnt lgkmcnt(0)" ::: "memory");  // writes landed
    __builtin_amdgcn_s_barrier();                       // tile visible
    asm volatile("" ::: "memory");
    if (step + 1 < 16) {  // issue next-tile loads; wait is next ds_write
      int koff = (step + 1) * 64;
#pragma unroll
      for (int i = 0; i < 4; i++) {
        sA[i] = *(const bf16x8*)(Ab + (size_t)(i * 8) * Kd + koff);
        sB[i] = *(const bf16x8*)(Bb + (size_t)(i * 8) * Kd + koff);
      }
    }
#pragma unroll
    for (int kc = 0; kc < 2; kc++) {
      bf16x8 af[4], bf[4];
#pragma unroll
      for (int i = 0; i < 4; i++)
        af[i] = *(const bf16x8*)&As[(wy * 64 + i * 16 + lc) * 64 +
                                    ((kc * 4 + quad) ^ rx) * 8];
#pragma unroll
      for (int i = 0; i < 4; i++)
        bf[i] = *(const bf16x8*)&Bs[(wx * 64 + i * 16 + lc) * 64 +
                                    ((kc * 4 + quad) ^ rx) * 8];
#pragma unroll
      for (int mi = 0; mi < 4; mi++)
#pragma unroll
        for (int ni = 0; ni < 4; ni++)
          acc[mi][ni] = __builtin_amdgcn_mfma_f32_16x16x32_bf16(af[mi], bf[ni], acc[mi][ni], 0, 0, 0);
    }
    asm volatile("s_waitcnt lgkmcnt(0)" ::: "memory");  // reads drained
    __builtin_amdgcn_s_barrier();                       // before overwrite
    asm volatile("" ::: "memory");
  }
#pragma unroll
  for (int mi = 0; mi < 4; mi++) {
    int row = m0 + wy * 64 + mi * 16 + quad * 4;
#pragma unroll
    for (int ni = 0; ni < 4; ni++) {
      int col = n0 + wx * 64 + ni * 16 + lc;
      int which = col >> 10;  // block-uniform (n-tile never straddles 1024)
      int hd = col & 1023;
      int h = hd >> 6, d = hd & 63;
      float bb = (which == 0) ? bq[hd] : (which == 1) ? bk[hd] : bv[hd];
      if (which == 2) {  // V^T [b,h,d,t], pack 4 consecutive t
        alignas(8) short pk[4];
#pragma unroll
        for (int r = 0; r < 4; r++) pk[r] = f2bf(acc[mi][ni][r] + bb);
        int b = row >> 11, tt = row & 2047;
        *(int2*)&Vo[((size_t)(b * 16 + h) * 64 + d) * 2048 + tt] = *(const int2*)pk;
      } else {
#pragma unroll
        for (int r = 0; r < 4; r++) {
          int rw = row + r;
          int b = rw >> 11, tt = rw & 2047;
          float val = acc[mi][ni][r] + bb;
          if (which == 0) {
            Qo[((size_t)(b * 16 + h) * 2048 + tt) * 64 + d] = f2bf(val * QSCL);
          } else {
            Ko[((size_t)(b * 16 + h) * 2048 + tt) * 64 + d] = f2bf(val);
          }
        }
      }
    }
  }
}

// ---------------- out-projection GEMM (reg-staged, BK=64) ----------------
// A = attended [4096][1024] bf16, Wt = Wo^T [1024][1024], out fp32.
// 64x128 tile, grid (64,8) = 512 blocks; R13-style reg-staged pipeline.

__global__ __launch_bounds__(BLOCK) void gemm_out_kernel(
    const short* __restrict__ A, const short* __restrict__ Wt,
    const float* __restrict__ bias, float* __restrict__ Out) {
  const int Kd = 1024;
  int m0 = blockIdx.x * 64, n0 = blockIdx.y * 128;
  int t = threadIdx.x;
  int lane = t & 63, wv = t >> 6;
  int quad = lane >> 4, lc = lane & 15;
  int wy = wv >> 1, wx = wv & 1;  // wave tile: rows wy*32, cols wx*64
  __shared__ short As[64 * 64];   // 8KB, [row][slot^swz]
  __shared__ short Bs[128 * 64];  // 16KB
  f32x4 acc[2][4] = {};

  // staging: A rows wv*16 + i*8 + (lane>>3) (i=0,1); B rows wv*32 + i*8*? (i=0..3)
  int lr = lane >> 3;      // 0..7
  int schk = lane & 7;     // linear global 16B chunk
  int wslot = schk ^ lr;   // row&7 == lr for all staged rows
  int srA = wv * 16 + lr;
  int srB = wv * 32 + lr;
  const short* Ab = A + (size_t)(m0 + srA) * Kd + schk * 8;
  const short* Bb = Wt + (size_t)(n0 + srB) * Kd + schk * 8;
  short* wa = &As[srA * 64 + wslot * 8];
  short* wb = &Bs[srB * 64 + wslot * 8];

  bf16x8 sA[2], sB[4];
#pragma unroll
  for (int i = 0; i < 2; i++) sA[i] = *(const bf16x8*)(Ab + (size_t)(i * 8) * Kd);
#pragma unroll
  for (int i = 0; i < 4; i++) sB[i] = *(const bf16x8*)(Bb + (size_t)(i * 8) * Kd);

  int rx = lc & 7;  // reader xor: row = *+i*16+lc -> row&7 == lc&7
  for (int step = 0; step < 16; step++) {
#pragma unroll
    for (int i = 0; i < 2; i++) *(bf16x8*)(wa + i * 8 * 64) = sA[i];
#pragma unroll
    for (int i = 0; i < 4; i++) *(bf16x8*)(wb + i * 8 * 64) = sB[i];
    asm volatile("s_waitcnt lgkmcnt(0)" ::: "memory");
    __builtin_amdgcn_s_barrier();
    asm volatile("" ::: "memory");
    if (step + 1 < 16) {
      int koff = (step + 1) * 64;
#pragma unroll
      for (int i = 0; i < 2; i++)
        sA[i] = *(const bf16x8*)(Ab + (size_t)(i * 8) * Kd + koff);
#pragma unroll
      for (int i = 0; i < 4; i++)
        sB[i] = *(const bf16x8*)(Bb + (size_t)(i * 8) * Kd + koff);
    }
#pragma unroll
    for (int kc = 0; kc < 2; kc++) {
      bf16x8 af[2], bf[4];
#pragma unroll
      for (int i = 0; i < 2; i++)
        af[i] = *(const bf16x8*)&As[(wy * 32 + i * 16 + lc) * 64 +
                                    ((kc * 4 + quad) ^ rx) * 8];
#pragma unroll
      for (int i = 0; i < 4; i++)
        bf[i] = *(const bf16x8*)&Bs[(wx * 64 + i * 16 + lc) * 64 +
                                    ((kc * 4 + quad) ^ rx) * 8];
#pragma unroll
      for (int mi = 0; mi < 2; mi++)
#pragma unroll
        for (int ni = 0; ni < 4; ni++)
          acc[mi][ni] = __builtin_amdgcn_mfma_f32_16x16x32_bf16(af[mi], bf[ni], acc[mi][ni], 0, 0, 0);
    }
    asm volatile("s_waitcnt lgkmcnt(0)" ::: "memory");
    __builtin_amdgcn_s_barrier();
    asm volatile("" ::: "memory");
  }
#pragma unroll
  for (int mi = 0; mi < 2; mi++) {
    int row = m0 + wy * 32 + mi * 16 + quad * 4;
#pragma unroll
    for (int ni = 0; ni < 4; ni++) {
      int col = n0 + wx * 64 + ni * 16 + lc;
      float bb = bias[col];
#pragma unroll
      for (int r = 0; r < 4; r++)
        Out[(size_t)(row + r) * 1024 + col] = acc[mi][ni][r] + bb;
    }
  }
}

// ---------------- flash attention v12 (reg-staged K/V) ----------------
// = v11 structure + R13 pipeline: single-buffer K/V LDS; next tile staged
// into VGPRs before compute, ds_write after the end-of-compute barrier.
// No vmcnt drain anywhere in the tile loop. XCD remap, xor-swizzled
// stride-64 K/V LDS, fixed-max softmax (exp2(s2-14.5)) unchanged.

__global__ __launch_bounds__(BLOCK, 2) void attn_kernel(
    const short* __restrict__ Q, const short* __restrict__ K,
    const short* __restrict__ Vt, short* __restrict__ Oa) {
  int p = blockIdx.x;
  int bh = ((p & 7) << 2) | ((p >> 3) & 3);  // same bh -> same XCD (p%8)
  int pair = p >> 5;                         // 0..15
  int t = threadIdx.x;
  int lane = t & 63, w = t >> 6;
  int qh = w & 1, kh = w >> 1;
  int ln = lane & 31, lh = lane >> 5;
  const short* Qb = Q + (size_t)bh * 2048 * 64;
  const short* Kb = K + (size_t)bh * 2048 * 64;
  const short* Vg = Vt + (size_t)bh * 64 * 2048;
  int b = bh >> 4, h = bh & 15;

  __shared__ short Kt[64 * 64];  // [key][chunk-swizzled d], stride 64 (single buf)
  __shared__ short Vs[64 * 64];  // [d][chunk-swizzled key], stride 64
  __shared__ __align__(16) short Ps[4][32 * 72];  // per-wave P; reused as fp32 O-combine
  __shared__ float lx[2][64];
  short* Pw = Ps[w];

  int srow = t >> 3;                 // staging row sub-index 0..31
  int schk = t & 7;                  // linear global 16B chunk
  int wslot = (schk ^ (srow & 7)) * 8;  // swizzled LDS slot; (i*32+srow)&7 == srow&7
  const float M2 = 14.5f;            // fixed softmax max, log2 domain
  int xk = ln & 7;                   // reader xor (row&7)

  for (int sp = 0; sp < 2; sp++) {
    int s = sp ? (31 - pair) : pair;
    int q0 = s * 64;
    int q0w = q0 + qh * 32;
    int qmaxw = q0w + 31;
    int ntiles = s + 1;

    // Q B-frags (n=q, k=d), 4 chunks of 16 d
    bf16x8 qf[4];
#pragma unroll
    for (int c = 0; c < 4; c++)
      qf[c] = *(const bf16x8*)&Qb[(size_t)(q0w + ln) * 64 + c * 16 + lh * 8];

    f32x16 O0 = {}, O1 = {};
    float lsum = 0.f;

    // prologue: stage tile 0 into regs (linear chunks; swizzle at ds_write)
    bf16x8 sK[2], sV[2];
#pragma unroll
    for (int i = 0; i < 2; i++) {
      int r = i * 32 + srow;
      sK[i] = *(const bf16x8*)&Kb[(size_t)r * 64 + schk * 8];
      sV[i] = *(const bf16x8*)&Vg[(size_t)r * 2048 + schk * 8];
    }
    for (int kt = 0; kt < ntiles; kt++) {
      // ds_write staged tile (compiler-placed vmcnt wait lands here, after
      // the previous tile's full compute phase)
#pragma unroll
      for (int i = 0; i < 2; i++) {
        int r = i * 32 + srow;
        *(bf16x8*)&Kt[r * 64 + wslot] = sK[i];
        *(bf16x8*)&Vs[r * 64 + wslot] = sV[i];
      }
      asm volatile("s_waitcnt lgkmcnt(0)" ::: "memory");  // writes landed
      __builtin_amdgcn_s_barrier();                       // tile visible
      asm volatile("" ::: "memory");
      if (kt + 1 < ntiles) {  // issue next-tile loads -> regs
        int kb2 = (kt + 1) * 64;
#pragma unroll
        for (int i = 0; i < 2; i++) {
          int r = i * 32 + srow;
          sK[i] = *(const bf16x8*)&Kb[(size_t)(kb2 + r) * 64 + schk * 8];
          sV[i] = *(const bf16x8*)&Vg[(size_t)r * 2048 + kb2 + schk * 8];
        }
      }
      int grpbase = kt * 64 + kh * 32;  // wave-uniform 32-key group
      if (grpbase <= qmaxw) {           // wave active on this tile
        // S^T = K(group) * Q^T : C[m=key32][n=q32]
        f32x16 S = {};
#pragma unroll
        for (int c = 0; c < 4; c++) {
          int ch = c * 2 + lh;  // 16B d-chunk index
          bf16x8 kf = *(const bf16x8*)&Kt[(kh * 32 + ln) * 64 + (ch ^ xk) * 8];
          S = __builtin_amdgcn_mfma_f32_32x32x16_bf16(kf, qf[c], S, 0, 0, 0);
        }
        if (kt == ntiles - 1) {  // diagonal tile: mask key > q
          int qg = q0w + ln;
#pragma unroll
          for (int reg = 0; reg < 16; reg++) {
            int key = grpbase + (reg & 3) + 8 * (reg >> 2) + 4 * lh;
            if (key > qg) S[reg] = -3.0e38f;
          }
        }
        // p = exp2(s - M2); accumulate l; pack 4 keys -> b64 (slots 0..31)
#pragma unroll
        for (int g = 0; g < 4; g++) {
          unsigned u[4];
#pragma unroll
          for (int i = 0; i < 4; i++) {
            union { float f; unsigned v; } cc;
            cc.f = __builtin_amdgcn_exp2f(S[g * 4 + i] - M2);
            lsum += cc.f;
            u[i] = cc.v + 0x8000u;  // round-half-up before truncate
          }
          int2 pk;
          pk.x = (int)__builtin_amdgcn_perm(u[1], u[0], 0x07060302);
          pk.y = (int)__builtin_amdgcn_perm(u[3], u[2], 0x07060302);
          *(int2*)&Pw[ln * 72 + g * 8 + lh * 4] = pk;
        }
        // PV over this wave's 32 keys (per-wave LDS, in-order, no barrier)
#pragma unroll
        for (int c2 = 0; c2 < 2; c2++) {
          bf16x8 pf = *(const bf16x8*)&Pw[ln * 72 + c2 * 16 + lh * 8];
          int ch = kh * 4 + c2 * 2 + lh;  // 16B key-chunk within tile
          bf16x8 v0 = *(const bf16x8*)&Vs[ln * 64 + (ch ^ xk) * 8];
          bf16x8 v1 = *(const bf16x8*)&Vs[(32 + ln) * 64 + (ch ^ xk) * 8];
          O0 = __builtin_amdgcn_mfma_f32_32x32x16_bf16(v0, pf, O0, 0, 0, 0);
          O1 = __builtin_amdgcn_mfma_f32_32x32x16_bf16(v1, pf, O1, 0, 0, 0);
        }
      }
      asm volatile("s_waitcnt lgkmcnt(0)" ::: "memory");  // reads drained
      __builtin_amdgcn_s_barrier();                       // before next overwrite
      asm volatile("" ::: "memory");
    }

    // ---- combine keyhalf partials through LDS (P region is dead) ----
    float* ob = (float*)&Ps[0][0];  // [qh][((dh*16+reg)*2+lh)*32+ln] fp32
    if (kh == 1) {
      float* obw = ob + qh * 2048;
#pragma unroll
      for (int dh = 0; dh < 2; dh++)
#pragma unroll
        for (int reg = 0; reg < 16; reg++)
          obw[((dh * 16 + reg) * 2 + lh) * 32 + ln] = dh ? O1[reg] : O0[reg];
      lx[qh][lane] = lsum;
    }
    __syncthreads();
    if (kh == 0) {
      float* obw = ob + qh * 2048;
#pragma unroll
      for (int reg = 0; reg < 16; reg++) {
        O0[reg] += obw[((0 * 16 + reg) * 2 + lh) * 32 + ln];
        O1[reg] += obw[((1 * 16 + reg) * 2 + lh) * 32 + ln];
      }
      float lt = lsum + lx[qh][lane];
      lt += __shfl_xor(lt, 32, 64);
      float inv = 1.0f / lt;
      size_t rowbase = (size_t)(b * 2048 + q0w + ln) * 1024 + h * 64;
#pragma unroll
      for (int dh = 0; dh < 2; dh++)
#pragma unroll
        for (int g = 0; g < 4; g++) {
          alignas(8) short pk[4];
#pragma unroll
          for (int i = 0; i < 4; i++) {
            float v = dh ? O1[g * 4 + i] : O0[g * 4 + i];
            pk[i] = f2bf(v * inv);
          }
          *(int2*)&Oa[rowbase + dh * 32 + g * 8 + lh * 4] = *(const int2*)pk;
        }
    }
    // next strip's first barrier orders Kt/Vs & Ps reuse after ob/lx reads
  }
}

// ---------------- launcher ----------------

extern "C" void kernel_launch(void* const* d_in, const int* in_sizes, int n_in,
                              void* d_out, int out_size, void* d_ws, size_t ws_size,
                              hipStream_t stream) {
  const float* x = (const float*)d_in[0];
  const float* Wq = (const float*)d_in[1];
  const float* bq = (const float*)d_in[2];
  const float* Wk = (const float*)d_in[3];
  const float* bk = (const float*)d_in[4];
  const float* Wv = (const float*)d_in[5];
  const float* bv = (const float*)d_in[6];
  const float* Wo = (const float*)d_in[7];
  const float* bo = (const float*)d_in[8];
  char* ws = (char*)d_ws;
  const size_t MB = 1024 * 1024;
  short* xb = (short*)(ws);               // 8 MiB  [4096][1024] bf16
  short* Wtqkv = (short*)(ws + 8 * MB);   // 6 MiB  [3072][1024] bf16
  short* Wto = (short*)(ws + 14 * MB);    // 2 MiB  [1024][1024] bf16
  short* Qb = (short*)(ws + 17 * MB);     // 8 MiB  [2][16][2048][64] bf16 (prescaled)
  short* Kb = (short*)(ws + 25 * MB);     // 8 MiB  [2][16][2048][64] bf16
  short* Vb = (short*)(ws + 33 * MB);     // 8 MiB  V^T [2][16][64][2048] bf16
  short* Att = (short*)(ws + 41 * MB);    // 8 MiB  [4096][1024] bf16
  float* out = (float*)d_out;

  cvt_all_kernel<<<dim3(32, 32, 6), BLOCK, 0, stream>>>(x, Wq, Wk, Wv, Wo, xb, Wtqkv, Wto);
  gemm_qkv_kernel<<<dim3(768), BLOCK, 0, stream>>>(xb, Wtqkv, bq, bk, bv, Qb, Kb, Vb);
  attn_kernel<<<512, BLOCK, 0, stream>>>(Qb, Kb, Vb, Att);
  gemm_out_kernel<<<dim3(64, 8), BLOCK, 0, stream>>>(Att, Wto, bo, out);
}